// Round 6
// baseline (268.012 us; speedup 1.0000x reference)
//
#include <hip/hip_runtime.h>
#include <stdint.h>

#define BB 128
#define NN 32768
#define CI 6
#define TOPK 400
#define KEEPK 200
#define CAND 1024
#define NTA 1024
#define NTB 1024
#define HALF 16384
#define SUPS 9          // supm row stride in ULLs (9*8=72B -> <=4-way LDS conflicts)
#define NTASK 1744      // sum over w4 of min(400, 64*(w4+1))

__device__ __forceinline__ unsigned long long rl64(unsigned long long v, int src) {
    unsigned int lo = (unsigned int)(v & 0xFFFFFFFFull);
    unsigned int hi = (unsigned int)(v >> 32);
    unsigned int l2 = (unsigned int)__builtin_amdgcn_readlane((int)lo, src);
    unsigned int h2 = (unsigned int)__builtin_amdgcn_readlane((int)hi, src);
    return (((unsigned long long)h2) << 32) | (unsigned long long)l2;
}

// ---------------- Kernel A: per-half-image top-400 (full GPU, 256 blocks) ---
// Direct register loads: thread t's float4s [3t+1],[3t+2] of a 2048-row tile
// hold the conf pairs of rows 2t,2t+1 (24B rows / 16B chunks align every 48B).
// Same HBM lines as full read; no LDS staging, no barriers in streaming.
__global__ __launch_bounds__(NTA) void half_select_kernel(
        const float* __restrict__ pred, unsigned long long* __restrict__ ws) {
    const int blk = blockIdx.x, b = blk >> 1, h = blk & 1;
    const int tid = threadIdx.x, lane = tid & 63, wid = tid >> 6;
    const float4* f4 = (const float4*)(pred + (size_t)b * (NN * CI));
    const int fbase = h * 24576;                  // (h*16384 rows)*6 floats /4

    __shared__ unsigned long long cbuf[CAND];
    __shared__ unsigned int redbuf[16];
    __shared__ unsigned int sh_cnt, ccount;

    uint32_t kreg[16];
    {   // prefetch-1 across 8 tiles of 2048 rows
        int b0 = fbase + 3 * tid;
        float4 a1 = f4[b0 + 1], a2 = f4[b0 + 2];
#pragma unroll
        for (int u = 0; u < 8; ++u) {
            float4 n1, n2;
            if (u < 7) {
                int nb = fbase + (u + 1) * 3072 + 3 * tid;
                n1 = f4[nb + 1]; n2 = f4[nb + 2];
            }
            float s0 = fmaxf(a1.x, a1.y);         // conf of row 2t
            float s1 = fmaxf(a2.z, a2.w);         // conf of row 2t+1
            kreg[2 * u]     = (s0 > 0.5f) ? __float_as_uint(s0) : 0u;
            kreg[2 * u + 1] = (s1 > 0.5f) ? __float_as_uint(s1) : 0u;
            a1 = n1; a2 = n2;
        }
    }

    // ---- bit-descend: find T with count(>=T) in [TOPK, CAND] (no atomics)
    unsigned int T = 0, cur = 0xFFFFFFFFu;
    for (int bit = 30; bit >= 0; --bit) {
        unsigned int T2 = T | (1u << bit);
        unsigned int c = 0;
#pragma unroll
        for (int u = 0; u < 16; ++u) c += (kreg[u] >= T2) ? 1u : 0u;
#pragma unroll
        for (int off = 32; off >= 1; off >>= 1) c += __shfl_down(c, off);
        if (lane == 0) redbuf[wid] = c;
        __syncthreads();
        if (tid == 0) {
            unsigned int tot = 0;
#pragma unroll
            for (int i = 0; i < 16; ++i) tot += redbuf[i];
            sh_cnt = tot;
        }
        __syncthreads();
        unsigned int tot = sh_cnt;
        if (tot >= TOPK) { T = T2; cur = tot; }
        if (cur >= TOPK && cur <= CAND && T != 0u) break;
    }
    if (T == 0u) T = 1u;                          // <400 positives: take all

    // ---- gather composites (key, ~idx) for keys >= T
    if (tid == 0) ccount = 0;
    cbuf[tid] = 0ull;
    __syncthreads();
#pragma unroll
    for (int u = 0; u < 16; ++u) {
        uint32_t key = kreg[u];
        if (key >= T) {
            unsigned int p = atomicAdd(&ccount, 1u);
            if (p < CAND) {
                unsigned int idx = (unsigned int)(h * HALF + (u >> 1) * 2048 + 2 * tid + (u & 1));
                cbuf[p] = ((unsigned long long)key << 32) |
                          (unsigned long long)(0xFFFFFFFFu - idx);
            }
        }
    }
    __syncthreads();

    // ---- bitonic sort 1024 desc (ties: lower idx first via ~idx low word)
    for (int kk = 2; kk <= CAND; kk <<= 1) {
        for (int j = kk >> 1; j > 0; j >>= 1) {
            int partner = tid ^ j;
            if (partner > tid) {
                unsigned long long a = cbuf[tid], c2 = cbuf[partner];
                if (((tid & kk) == 0) ? (a < c2) : (a > c2)) {
                    cbuf[tid] = c2; cbuf[partner] = a;
                }
            }
            __syncthreads();
        }
    }

    if (tid < TOPK) ws[(size_t)blk * TOPK + tid] = cbuf[tid];
}

// ---------------- Kernel B: merge halves + decode + NMS + output -----------
__global__ __launch_bounds__(NTB) void nms_kernel(
        const float* __restrict__ pred, const float* __restrict__ priors,
        const unsigned long long* __restrict__ ws, float* __restrict__ out) {
    const int b = blockIdx.x, tid = threadIdx.x;
    const int lane = tid & 63, wid = tid >> 6;
    const float* img = pred + (size_t)b * (NN * CI);
    float* oimg = out + (size_t)b * KEEPK * 6;

    __shared__ unsigned long long lA[TOPK], lB[TOPK], cbuf[TOPK];
    __shared__ float4 cbox[TOPK];
    __shared__ float car[TOPK], csc[TOPK];
    __shared__ int clab[TOPK];
    __shared__ __align__(16) unsigned long long supm[TOPK * SUPS];
    __shared__ unsigned long long keepw[8];

    for (int i = tid; i < KEEPK * 6; i += NTB) oimg[i] = 0.0f;
    if (tid < TOPK) {
        lA[tid] = ws[(size_t)(2 * b) * TOPK + tid];
        lB[tid] = ws[(size_t)(2 * b + 1) * TOPK + tid];
        cbuf[tid] = 0ull;
    }
    if (tid < 8) keepw[tid] = 0ull;
    __syncthreads();

    // ---- merge-by-rank: union's t-th largest (composites unique; 0 invalid)
    if (tid < TOPK) {
        unsigned long long v = lA[tid];
        if (v) {
            int lo = 0, hi = TOPK;
            while (lo < hi) { int mid = (lo + hi) >> 1; if (lB[mid] > v) lo = mid + 1; else hi = mid; }
            int rank = tid + lo;
            if (rank < TOPK) cbuf[rank] = v;
        }
        unsigned long long w = lB[tid];
        if (w) {
            int lo = 0, hi = TOPK;
            while (lo < hi) { int mid = (lo + hi) >> 1; if (lA[mid] > w) lo = mid + 1; else hi = mid; }
            int rank = tid + lo;
            if (rank < TOPK) cbuf[rank] = w;
        }
    }
    __syncthreads();

    // ---- decode candidates (reference float op order; no fma)
    if (tid < TOPK) {
        const int t = tid;
        unsigned long long c = cbuf[t];
        uint32_t key = (uint32_t)(c >> 32);
        uint32_t idx = 0xFFFFFFFFu - (uint32_t)(c & 0xFFFFFFFFull);
        int valid = (key != 0u) && (idx < NN);
        float x1 = 0.f, y1 = 0.f, x2 = 0.f, y2 = 0.f;
        int lab = 0;
        if (valid) {
            const float* p = img + (size_t)idx * CI;
            float l0 = p[0], l1 = p[1], l2 = p[2], l3 = p[3], c0 = p[4], c1 = p[5];
            const float* pr = priors + (size_t)idx * 4;
            float px = pr[0], py = pr[1], pw = pr[2], ph = pr[3];
            float cxv = __fadd_rn(px, __fmul_rn(__fmul_rn(l0, 0.1f), pw));
            float cyv = __fadd_rn(py, __fmul_rn(__fmul_rn(l1, 0.1f), ph));
            float ew = __fmul_rn(pw, expf(__fmul_rn(l2, 0.2f)));
            float eh = __fmul_rn(ph, expf(__fmul_rn(l3, 0.2f)));
            float hw = __fmul_rn(ew, 0.5f);
            float hh = __fmul_rn(eh, 0.5f);
            x1 = __fsub_rn(cxv, hw); y1 = __fsub_rn(cyv, hh);
            x2 = __fadd_rn(cxv, hw); y2 = __fadd_rn(cyv, hh);
            lab = (c1 > c0) ? 1 : 0;
        }
        cbox[t] = make_float4(x1, y1, x2, y2);
        csc[t] = __uint_as_float(key);
        car[t] = __fmul_rn(__fsub_rn(x2, x1), __fsub_rn(y2, y1));
        clab[t] = lab;
        if (valid) atomicOr(&keepw[t >> 6], 1ull << (t & 63));
    }
    __syncthreads();

    // ---- suppression bit-matrix via ballot: task = (row i, word w4)
    // lane = j - 64*w4 -> cbox reads are 64 consecutive float4s (conflict-free)
    for (int task = wid; task < NTASK; task += NTB / 64) {
        int w4, off;
        if      (task < 64)   { w4 = 0; off = 0; }
        else if (task < 192)  { w4 = 1; off = 64; }
        else if (task < 384)  { w4 = 2; off = 192; }
        else if (task < 640)  { w4 = 3; off = 384; }
        else if (task < 960)  { w4 = 4; off = 640; }
        else if (task < 1344) { w4 = 5; off = 960; }
        else                  { w4 = 6; off = 1344; }
        int i = task - off;                       // row; word w4 >= i>>6 by construction
        int j = (w4 << 6) + lane;
        float4 bi = cbox[i]; float ai = car[i];   // uniform -> broadcast
        bool p = false;
        if (j < TOPK && j > i) {
            float4 bj = cbox[j]; float aj = car[j];
            float iw = fmaxf(__fsub_rn(fminf(bi.z, bj.z), fmaxf(bi.x, bj.x)), 0.0f);
            float ih = fmaxf(__fsub_rn(fminf(bi.w, bj.w), fmaxf(bi.y, bj.y)), 0.0f);
            float inter = __fmul_rn(iw, ih);
            float denom = __fadd_rn(__fsub_rn(__fadd_rn(ai, aj), inter), 1e-12f);
            p = (__fdiv_rn(inter, denom) > 0.5f);
        }
        unsigned long long word = __ballot(p);
        if (lane == 0) supm[i * SUPS + w4] = word;
    }
    __syncthreads();

    // ---- sequential resolve: wave 0, lane r holds row 64W+r in registers;
    // the 400-step chain runs on registers via readlane (no LDS/shuffle latency)
    if (wid == 0) {
        unsigned long long kw0 = keepw[0], kw1 = keepw[1], kw2 = keepw[2],
                           kw3 = keepw[3], kw4 = keepw[4], kw5 = keepw[5], kw6 = keepw[6];
        unsigned long long rem0 = 0, rem1 = 0, rem2 = 0, rem3 = 0, rem4 = 0, rem5 = 0, rem6 = 0;
#define RESOLVE_CHUNK(W, KW, REMW, ORLIST)                                      \
        {                                                                       \
            unsigned long long q0 = 0, q1 = 0, q2 = 0, q3 = 0, q4 = 0, q5 = 0, q6 = 0; \
            int r = ((W) << 6) + lane;                                          \
            if (r < TOPK) {                                                     \
                const unsigned long long* rp = &supm[r * SUPS];                 \
                q0 = rp[0]; q1 = rp[1]; q2 = rp[2]; q3 = rp[3];                 \
                q4 = rp[4]; q5 = rp[5]; q6 = rp[6];                             \
            }                                                                   \
            for (int bit = 0; bit < 64; ++bit) {                                \
                if (((KW & ~REMW) >> bit) & 1ull) { ORLIST }                    \
            }                                                                   \
        }
        RESOLVE_CHUNK(0, kw0, rem0,
            rem0 |= rl64(q0, bit); rem1 |= rl64(q1, bit); rem2 |= rl64(q2, bit);
            rem3 |= rl64(q3, bit); rem4 |= rl64(q4, bit); rem5 |= rl64(q5, bit);
            rem6 |= rl64(q6, bit);)
        RESOLVE_CHUNK(1, kw1, rem1,
            rem1 |= rl64(q1, bit); rem2 |= rl64(q2, bit); rem3 |= rl64(q3, bit);
            rem4 |= rl64(q4, bit); rem5 |= rl64(q5, bit); rem6 |= rl64(q6, bit);)
        RESOLVE_CHUNK(2, kw2, rem2,
            rem2 |= rl64(q2, bit); rem3 |= rl64(q3, bit); rem4 |= rl64(q4, bit);
            rem5 |= rl64(q5, bit); rem6 |= rl64(q6, bit);)
        RESOLVE_CHUNK(3, kw3, rem3,
            rem3 |= rl64(q3, bit); rem4 |= rl64(q4, bit); rem5 |= rl64(q5, bit);
            rem6 |= rl64(q6, bit);)
        RESOLVE_CHUNK(4, kw4, rem4,
            rem4 |= rl64(q4, bit); rem5 |= rl64(q5, bit); rem6 |= rl64(q6, bit);)
        RESOLVE_CHUNK(5, kw5, rem5,
            rem5 |= rl64(q5, bit); rem6 |= rl64(q6, bit);)
        RESOLVE_CHUNK(6, kw6, rem6,
            rem6 |= rl64(q6, bit);)
#undef RESOLVE_CHUNK
        if (lane == 0) {
            keepw[0] = kw0 & ~rem0; keepw[1] = kw1 & ~rem1; keepw[2] = kw2 & ~rem2;
            keepw[3] = kw3 & ~rem3; keepw[4] = kw4 & ~rem4; keepw[5] = kw5 & ~rem5;
            keepw[6] = kw6 & ~rem6; keepw[7] = 0ull;
        }
    }
    __syncthreads();

    // ---- output: kept sorted ascending by (score, position), first 200 rows
    if (tid < TOPK) {
        const int t = tid;
        if ((keepw[t >> 6] >> (t & 63)) & 1ull) {
            float st = csc[t];
            int rank = 0;
            for (int j = 0; j < TOPK; j++) {
                bool kj = (keepw[j >> 6] >> (j & 63)) & 1ull;
                float sj = csc[j];
                if (kj && (sj < st || (sj == st && j < t))) rank++;
            }
            if (rank < KEEPK) {
                float4 bx = cbox[t];
                float* row = oimg + (size_t)rank * 6;
                row[0] = (float)clab[t];
                row[1] = st;
                row[2] = bx.x; row[3] = bx.y; row[4] = bx.z; row[5] = bx.w;
            }
        }
    }
}

extern "C" void kernel_launch(void* const* d_in, const int* in_sizes, int n_in,
                              void* d_out, int out_size, void* d_ws, size_t ws_size,
                              hipStream_t stream) {
    const float* pred = (const float*)d_in[0];     // (128, 32768, 6)
    const float* priors = (const float*)d_in[1];   // (32768, 4)
    float* out = (float*)d_out;                    // (128, 200, 6)
    unsigned long long* ws = (unsigned long long*)d_ws;   // 256*400*8 = 819 KB

    half_select_kernel<<<2 * BB, NTA, 0, stream>>>(pred, ws);
    nms_kernel<<<BB, NTB, 0, stream>>>(pred, priors, ws, out);
}

// Round 7
// 267.003 us; speedup vs baseline: 1.0038x; 1.0038x over previous
//
#include <hip/hip_runtime.h>
#include <stdint.h>

#define BB 128
#define NN 32768
#define CI 6
#define TOPK 400
#define KEEPK 200
#define CAND 512
#define QROWS 8192
#define NTA 256
#define NHIST 4096
#define SUPS 9          // supm row stride in ULLs
#define NTASK 1744      // sum over w4 of min(400, 64*(w4+1))

__device__ __forceinline__ unsigned long long rl64(unsigned long long v, int src) {
    unsigned int lo = (unsigned int)(v & 0xFFFFFFFFull);
    unsigned int hi = (unsigned int)(v >> 32);
    unsigned int l2 = (unsigned int)__builtin_amdgcn_readlane((int)lo, src);
    unsigned int h2 = (unsigned int)__builtin_amdgcn_readlane((int)hi, src);
    return (((unsigned long long)h2) << 32) | (unsigned long long)l2;
}

// ---------------- Kernel A: per-quarter-image top-400 (512 blocks) ---------
// Thread t's float4s [3t+1],[3t+2] of a 512-row tile hold conf pairs of rows
// 2t,2t+1. Deep prefetch: 16 loads in flight. Threshold T from a single
// 4096-bucket histogram on (bits - 0x3F000000)>>14 (scores>0.5 => bits >
// 0x3F000000); crossing bucket's lower edge gives count(>=T) in [400,~450].
__global__ __launch_bounds__(NTA) void quarter_select_kernel(
        const float* __restrict__ pred, unsigned long long* __restrict__ ws) {
    const int blk = blockIdx.x, b = blk >> 2, q = blk & 3;
    const int tid = threadIdx.x, lane = tid & 63, wid = tid >> 6;
    const float4* f4 = (const float4*)(pred + (size_t)b * (NN * CI));
    const int qf = q * (QROWS * CI / 4);           // quarter base in float4s

    __shared__ unsigned int hist[NHIST];
    __shared__ unsigned int wavetot[4];
    __shared__ unsigned int sh_bucket, ccount;
    __shared__ unsigned long long cbuf[CAND];

    for (int i = tid; i < NHIST; i += NTA) hist[i] = 0;
    if (tid == 0) { sh_bucket = 0xFFFFFFFFu; ccount = 0; }
    cbuf[tid] = 0ull; cbuf[tid + NTA] = 0ull;

    uint32_t kreg[32];
    for (int c = 0; c < 2; ++c) {                  // 2 chunks x 8 tiles x 2 rows
        float4 A1[8], A2[8];
        const int tb = qf + c * 6144 + 3 * tid;
#pragma unroll
        for (int u = 0; u < 8; ++u) { A1[u] = f4[tb + u * 768 + 1]; A2[u] = f4[tb + u * 768 + 2]; }
#pragma unroll
        for (int u = 0; u < 8; ++u) {
            float s0 = fmaxf(A1[u].x, A1[u].y);    // row 2t of tile
            float s1 = fmaxf(A2[u].z, A2[u].w);    // row 2t+1
            kreg[c * 16 + 2 * u]     = (s0 > 0.5f) ? __float_as_uint(s0) : 0u;
            kreg[c * 16 + 2 * u + 1] = (s1 > 0.5f) ? __float_as_uint(s1) : 0u;
        }
    }
    __syncthreads();

#pragma unroll
    for (int e = 0; e < 32; ++e) {
        uint32_t key = kreg[e];
        if (key) {
            unsigned int u = key - 0x3F000000u;    // key > 0x3F000000 always
            unsigned int bkt = u >> 14;
            if (bkt > NHIST - 1) bkt = NHIST - 1;
            atomicAdd(&hist[bkt], 1u);
        }
    }
    __syncthreads();

    {   // suffix scan: thread owns 16 buckets; find crossing of 400 from top
        unsigned int h[16], s = 0;
        const int base = tid * 16;
#pragma unroll
        for (int j = 0; j < 16; ++j) { h[j] = hist[base + j]; s += h[j]; }
        unsigned int suf = s;
#pragma unroll
        for (int off = 1; off < 64; off <<= 1) {
            unsigned int v = __shfl_down(suf, off);
            if (lane + off < 64) suf += v;
        }
        if (lane == 0) wavetot[wid] = suf;
        __syncthreads();
        if (tid == 0) {
            unsigned int w0 = wavetot[0], w1 = wavetot[1], w2 = wavetot[2], w3 = wavetot[3];
            (void)w0;
            wavetot[0] = w1 + w2 + w3; wavetot[1] = w2 + w3; wavetot[2] = w3; wavetot[3] = 0;
        }
        __syncthreads();
        unsigned int acc = wavetot[wid] + (suf - s);
#pragma unroll
        for (int j = 15; j >= 0; --j) {
            if (acc < TOPK && acc + h[j] >= TOPK) sh_bucket = (unsigned int)(base + j);
            acc += h[j];
        }
    }
    __syncthreads();
    const unsigned int beta = sh_bucket;
    const uint32_t T = (beta == 0xFFFFFFFFu) ? 1u : (0x3F000000u + (beta << 14));

    // gather composites (key, ~idx) for keys >= T (zeros excluded: T >= 1)
    for (int c = 0; c < 2; ++c)
#pragma unroll
        for (int u = 0; u < 8; ++u)
#pragma unroll
            for (int r = 0; r < 2; ++r) {
                uint32_t key = kreg[c * 16 + 2 * u + r];
                if (key >= T) {
                    unsigned int p = atomicAdd(&ccount, 1u);
                    if (p < CAND) {
                        unsigned int idx = (unsigned int)(q * QROWS + c * 4096 + u * 512 + 2 * tid + r);
                        cbuf[p] = ((unsigned long long)key << 32) |
                                  (unsigned long long)(0xFFFFFFFFu - idx);
                    }
                }
            }
    __syncthreads();

    // bitonic sort 512 desc (ties: lower idx first), 2 elements/thread
    for (int kk = 2; kk <= CAND; kk <<= 1) {
        for (int j = kk >> 1; j > 0; j >>= 1) {
            for (int i0 = tid; i0 < CAND; i0 += NTA) {
                int pr = i0 ^ j;
                if (pr > i0) {
                    unsigned long long a = cbuf[i0], c2 = cbuf[pr];
                    if (((i0 & kk) == 0) ? (a < c2) : (a > c2)) {
                        cbuf[i0] = c2; cbuf[pr] = a;
                    }
                }
            }
            __syncthreads();
        }
    }

    for (int t2 = tid; t2 < TOPK; t2 += NTA)
        ws[(size_t)blk * TOPK + t2] = cbuf[t2];
}

// ---------------- Kernel B1: 4-way merge + decode (256 blocks) -------------
__global__ __launch_bounds__(NTA) void merge_decode_kernel(
        const float* __restrict__ pred, const float* __restrict__ priors,
        const unsigned long long* __restrict__ ws, float4* __restrict__ ws2) {
    const int blk = blockIdx.x, b = blk >> 1, h = blk & 1;
    const int tid = threadIdx.x;
    const float* img = pred + (size_t)b * (NN * CI);

    __shared__ unsigned long long lAll[4 * TOPK];
    __shared__ unsigned long long cslot[KEEPK];

    const unsigned long long* wsb = ws + (size_t)(4 * b) * TOPK;
    for (int i = tid; i < 4 * TOPK; i += NTA) lAll[i] = wsb[i];
    for (int i = tid; i < KEEPK; i += NTA) cslot[i] = 0ull;
    __syncthreads();

    // exact rank of each element in the union (composites unique; 0 invalid)
    const int rlo = h * KEEPK, rhi = rlo + KEEPK;
    for (int i = tid; i < 4 * TOPK; i += NTA) {
        unsigned long long v = lAll[i];
        if (v) {
            int l = i / TOPK, pos = i - l * TOPK;
            int rank = pos;
#pragma unroll
            for (int m = 0; m < 4; ++m) {
                if (m == l) continue;
                const unsigned long long* L = &lAll[m * TOPK];
                int lo = 0, hi2 = TOPK;
                while (lo < hi2) { int mid = (lo + hi2) >> 1; if (L[mid] > v) lo = mid + 1; else hi2 = mid; }
                rank += lo;
            }
            if (rank >= rlo && rank < rhi) cslot[rank - rlo] = v;
        }
    }
    __syncthreads();

    // decode this block's 200 candidates (reference float op order; no fma)
    if (tid < KEEPK) {
        unsigned long long c = cslot[tid];
        uint32_t key = (uint32_t)(c >> 32);
        uint32_t idx = 0xFFFFFFFFu - (uint32_t)(c & 0xFFFFFFFFull);
        int valid = (key != 0u) && (idx < NN);
        float x1 = 0.f, y1 = 0.f, x2 = 0.f, y2 = 0.f;
        int lab = 0;
        if (valid) {
            const float* p = img + (size_t)idx * CI;
            float l0 = p[0], l1 = p[1], l2 = p[2], l3 = p[3], c0 = p[4], c1 = p[5];
            const float* pr = priors + (size_t)idx * 4;
            float px = pr[0], py = pr[1], pw = pr[2], ph = pr[3];
            float cxv = __fadd_rn(px, __fmul_rn(__fmul_rn(l0, 0.1f), pw));
            float cyv = __fadd_rn(py, __fmul_rn(__fmul_rn(l1, 0.1f), ph));
            float ew = __fmul_rn(pw, expf(__fmul_rn(l2, 0.2f)));
            float eh = __fmul_rn(ph, expf(__fmul_rn(l3, 0.2f)));
            float hw = __fmul_rn(ew, 0.5f);
            float hh = __fmul_rn(eh, 0.5f);
            x1 = __fsub_rn(cxv, hw); y1 = __fsub_rn(cyv, hh);
            x2 = __fadd_rn(cxv, hw); y2 = __fadd_rn(cyv, hh);
            lab = (c1 > c0) ? 1 : 0;
        }
        float area = __fmul_rn(__fsub_rn(x2, x1), __fsub_rn(y2, y1));
        size_t s = (size_t)b * TOPK + rlo + tid;
        ws2[2 * s]     = make_float4(x1, y1, x2, y2);
        ws2[2 * s + 1] = make_float4(__uint_as_float(key), area, (float)lab, valid ? 1.0f : 0.0f);
    }
}

// ---------------- Kernel B2: NMS + rank + output (128 blocks x 1024) -------
__global__ __launch_bounds__(1024) void nms_out_kernel(
        const float4* __restrict__ ws2, float* __restrict__ out) {
    const int b = blockIdx.x, tid = threadIdx.x;
    const int lane = tid & 63, wid = tid >> 6;
    float* oimg = out + (size_t)b * KEEPK * 6;

    __shared__ float4 cbox[TOPK];
    __shared__ float car[TOPK], csc[TOPK], clabf[TOPK];
    __shared__ int cvalid[TOPK];
    __shared__ __align__(16) unsigned long long supm[TOPK * SUPS];
    __shared__ unsigned long long keepw[8];
    __shared__ __align__(16) unsigned long long rkey[TOPK];

    for (int i = tid; i < KEEPK * 6; i += 1024) oimg[i] = 0.0f;
    if (tid < 2 * TOPK) {
        float4 v = ws2[(size_t)b * 2 * TOPK + tid];
        int slot = tid >> 1;
        if ((tid & 1) == 0) cbox[slot] = v;
        else { csc[slot] = v.x; car[slot] = v.y; clabf[slot] = v.z; cvalid[slot] = (v.w != 0.0f); }
    }
    if (tid == 0) keepw[7] = 0ull;
    __syncthreads();

    if (tid < 448) {                               // 7 full waves build keep words
        bool p = (tid < TOPK) ? (cvalid[tid] != 0) : false;
        unsigned long long wv = __ballot(p);
        if (lane == 0) keepw[wid] = wv;
    }
    __syncthreads();

    // suppression bit-matrix via ballot: task = (row i, word w4)
    for (int task = wid; task < NTASK; task += 16) {
        int w4, off;
        if      (task < 64)   { w4 = 0; off = 0; }
        else if (task < 192)  { w4 = 1; off = 64; }
        else if (task < 384)  { w4 = 2; off = 192; }
        else if (task < 640)  { w4 = 3; off = 384; }
        else if (task < 960)  { w4 = 4; off = 640; }
        else if (task < 1344) { w4 = 5; off = 960; }
        else                  { w4 = 6; off = 1344; }
        int i = task - off;
        int j = (w4 << 6) + lane;
        float4 bi = cbox[i]; float ai = car[i];    // uniform -> broadcast
        bool p = false;
        if (j < TOPK && j > i) {
            float4 bj = cbox[j]; float aj = car[j];
            float iw = fmaxf(__fsub_rn(fminf(bi.z, bj.z), fmaxf(bi.x, bj.x)), 0.0f);
            float ih = fmaxf(__fsub_rn(fminf(bi.w, bj.w), fmaxf(bi.y, bj.y)), 0.0f);
            float inter = __fmul_rn(iw, ih);
            float denom = __fadd_rn(__fsub_rn(__fadd_rn(ai, aj), inter), 1e-12f);
            p = (__fdiv_rn(inter, denom) > 0.5f);
        }
        unsigned long long word = __ballot(p);
        if (lane == 0) supm[i * SUPS + w4] = word;
    }
    __syncthreads();

    // sequential resolve: wave 0, rows in registers, readlane chain
    if (wid == 0) {
        unsigned long long kw0 = keepw[0], kw1 = keepw[1], kw2 = keepw[2],
                           kw3 = keepw[3], kw4 = keepw[4], kw5 = keepw[5], kw6 = keepw[6];
        unsigned long long rem0 = 0, rem1 = 0, rem2 = 0, rem3 = 0, rem4 = 0, rem5 = 0, rem6 = 0;
#define RESOLVE_CHUNK(W, KW, REMW, ORLIST)                                      \
        {                                                                       \
            unsigned long long q0 = 0, q1 = 0, q2 = 0, q3 = 0, q4 = 0, q5 = 0, q6 = 0; \
            int r = ((W) << 6) + lane;                                          \
            if (r < TOPK) {                                                     \
                const unsigned long long* rp = &supm[r * SUPS];                 \
                q0 = rp[0]; q1 = rp[1]; q2 = rp[2]; q3 = rp[3];                 \
                q4 = rp[4]; q5 = rp[5]; q6 = rp[6];                             \
            }                                                                   \
            for (int bit = 0; bit < 64; ++bit) {                                \
                if (((KW & ~REMW) >> bit) & 1ull) { ORLIST }                    \
            }                                                                   \
        }
        RESOLVE_CHUNK(0, kw0, rem0,
            rem0 |= rl64(q0, bit); rem1 |= rl64(q1, bit); rem2 |= rl64(q2, bit);
            rem3 |= rl64(q3, bit); rem4 |= rl64(q4, bit); rem5 |= rl64(q5, bit);
            rem6 |= rl64(q6, bit);)
        RESOLVE_CHUNK(1, kw1, rem1,
            rem1 |= rl64(q1, bit); rem2 |= rl64(q2, bit); rem3 |= rl64(q3, bit);
            rem4 |= rl64(q4, bit); rem5 |= rl64(q5, bit); rem6 |= rl64(q6, bit);)
        RESOLVE_CHUNK(2, kw2, rem2,
            rem2 |= rl64(q2, bit); rem3 |= rl64(q3, bit); rem4 |= rl64(q4, bit);
            rem5 |= rl64(q5, bit); rem6 |= rl64(q6, bit);)
        RESOLVE_CHUNK(3, kw3, rem3,
            rem3 |= rl64(q3, bit); rem4 |= rl64(q4, bit); rem5 |= rl64(q5, bit);
            rem6 |= rl64(q6, bit);)
        RESOLVE_CHUNK(4, kw4, rem4,
            rem4 |= rl64(q4, bit); rem5 |= rl64(q5, bit); rem6 |= rl64(q6, bit);)
        RESOLVE_CHUNK(5, kw5, rem5,
            rem5 |= rl64(q5, bit); rem6 |= rl64(q6, bit);)
        RESOLVE_CHUNK(6, kw6, rem6,
            rem6 |= rl64(q6, bit);)
#undef RESOLVE_CHUNK
        if (lane == 0) {
            keepw[0] = kw0 & ~rem0; keepw[1] = kw1 & ~rem1; keepw[2] = kw2 & ~rem2;
            keepw[3] = kw3 & ~rem3; keepw[4] = kw4 & ~rem4; keepw[5] = kw5 & ~rem5;
            keepw[6] = kw6 & ~rem6;
        }
    }
    __syncthreads();

    // rank keys: kept -> (scorebits, t) ascending; dropped -> max
    if (tid < TOPK) {
        bool kept = (keepw[tid >> 6] >> (tid & 63)) & 1ull;
        rkey[tid] = kept ? ((((unsigned long long)__float_as_uint(csc[tid])) << 32) |
                            (unsigned long long)(unsigned int)tid)
                         : 0xFFFFFFFFFFFFFFFFull;
    }
    __syncthreads();

    if (tid < TOPK && (((keepw[tid >> 6] >> (tid & 63)) & 1ull) != 0ull)) {
        unsigned long long my = rkey[tid];
        const ulonglong2* rk2 = (const ulonglong2*)rkey;
        int cnt = 0;
        for (int m = 0; m < TOPK / 2; ++m) {       // broadcast b128 LDS reads
            ulonglong2 pr = rk2[m];
            cnt += (pr.x < my) ? 1 : 0;
            cnt += (pr.y < my) ? 1 : 0;
        }
        if (cnt < KEEPK) {
            float4 bx = cbox[tid];
            float* row = oimg + (size_t)cnt * 6;
            row[0] = clabf[tid];
            row[1] = csc[tid];
            row[2] = bx.x; row[3] = bx.y; row[4] = bx.z; row[5] = bx.w;
        }
    }
}

extern "C" void kernel_launch(void* const* d_in, const int* in_sizes, int n_in,
                              void* d_out, int out_size, void* d_ws, size_t ws_size,
                              hipStream_t stream) {
    const float* pred = (const float*)d_in[0];     // (128, 32768, 6)
    const float* priors = (const float*)d_in[1];   // (32768, 4)
    float* out = (float*)d_out;                    // (128, 200, 6)
    unsigned long long* ws = (unsigned long long*)d_ws;            // 512*400*8 = 1.6 MB
    float4* ws2 = (float4*)((char*)d_ws + (size_t)512 * TOPK * 8); // 128*400*32 = 1.6 MB

    quarter_select_kernel<<<4 * BB, NTA, 0, stream>>>(pred, ws);
    merge_decode_kernel<<<2 * BB, NTA, 0, stream>>>(pred, priors, ws, ws2);
    nms_out_kernel<<<BB, 1024, 0, stream>>>(ws2, out);
}